// Round 5
// baseline (99.572 us; speedup 1.0000x reference)
//
#include <hip/hip_runtime.h>
#include <hip/hip_bf16.h>

#define BATCH 4096
#define NROWS 8192
#define DIM   128

typedef __bf16 bf16x8 __attribute__((ext_vector_type(8)));
typedef __bf16 bf16x2 __attribute__((ext_vector_type(2)));
typedef float  f32x4  __attribute__((ext_vector_type(4)));

// zn is stored k-major per 128-row tile: element (row r, col k) lives at
//   zn[ (r>>7)*16384 + (k>>3)*1024 + (r&127)*8 + (k&7) ]
// so an MFMA fragment load (16 rows x one 16B chunk) is 4x256B contiguous.

// ---------------------------------------------------------------------------
// Kernel 1: row-normalize z = concat(zx, zy) -> bf16 zn (k-major layout),
// and zero S[row]. One wave per row; lane holds 2 floats (cols 2l, 2l+1).
// ---------------------------------------------------------------------------
__global__ __launch_bounds__(256) void normalize_kernel(
    const float* __restrict__ zx, const float* __restrict__ zy,
    ushort* __restrict__ zn, float* __restrict__ S)
{
  const int tid  = threadIdx.x;
  const int lane = tid & 63;
  const int w    = tid >> 6;
  const int row  = blockIdx.x * 4 + w;
  const float* src = (row < BATCH) ? (zx + (size_t)row * DIM)
                                   : (zy + (size_t)(row - BATCH) * DIM);
  float2 v = ((const float2*)src)[lane];
  float ss = v.x * v.x + v.y * v.y;
#pragma unroll
  for (int off = 1; off < 64; off <<= 1)
    ss += __shfl_xor(ss, off, 64);
  float inv = 1.0f / fmaxf(sqrtf(ss), 1e-8f);
  bf16x2 st;
  st.x = (__bf16)(v.x * inv);
  st.y = (__bf16)(v.y * inv);
  // k-major scatter store: chunk = lane>>2, elem-in-chunk = (lane&3)*2
  ushort* dst = zn + (size_t)(row >> 7) * 16384 + (row & 127) * 8;
  *reinterpret_cast<bf16x2*>(dst + (lane >> 2) * 1024 + (lane & 3) * 2) = st;
  if (lane == 0) S[row] = 0.f;
}

// ---------------------------------------------------------------------------
// Kernel 2: symmetric fused sim-GEMM + exp-sum. One block per upper-tri
// 128x128 tile pair (rb <= cb), 2080 blocks (~8/CU). NO LDS, NO barriers:
// A/B fragments load coalesced from the k-major layout (L2-resident, 2 MB).
// Off-diagonal tiles feed both row sums S[i] and col sums S[j] (symmetry
// halves the MFMA work). Diagonal: self-term post-subtraction, row sums only.
// ---------------------------------------------------------------------------
__global__ __launch_bounds__(256, 3) void simloss_kernel(
    const ushort* __restrict__ zn, float* __restrict__ S, float* __restrict__ P)
{
  const int tid  = threadIdx.x;
  const int lane = tid & 63;
  const int w    = tid >> 6;
  const int wr   = w >> 1, wc = w & 1;
  const int q    = lane >> 4;
  const int l15  = lane & 15;

  // triangular decode: Offset(rb) = rb*(129-rb)/2
  const int t = blockIdx.x;
  int rb = (int)(0.5f * (129.0f - sqrtf((float)(16641 - 8 * t))));
  while (rb * (129 - rb) / 2 > t) --rb;
  while ((rb + 1) * (128 - rb) / 2 <= t) ++rb;
  const int cb = rb + (t - rb * (129 - rb) / 2);

  const int R0 = rb * 128, C0 = cb * 128;
  const bool diag = (rb == cb);
  const bool part = (cb == rb + 32);

  const ushort* At = zn + (size_t)rb * 16384;
  const ushort* Bt = zn + (size_t)cb * 16384;

  f32x4 acc[4][4];
#pragma unroll
  for (int mi = 0; mi < 4; ++mi)
#pragma unroll
    for (int ni = 0; ni < 4; ++ni)
      acc[mi][ni] = (f32x4){0.f, 0.f, 0.f, 0.f};

#pragma unroll
  for (int ks = 0; ks < 4; ++ks) {
    const int ck = (ks * 4 + q) * 1024;
    bf16x8 af[4], bf[4];
#pragma unroll
    for (int mi = 0; mi < 4; ++mi)
      af[mi] = *reinterpret_cast<const bf16x8*>(At + ck + (wr * 64 + mi * 16 + l15) * 8);
#pragma unroll
    for (int ni = 0; ni < 4; ++ni)
      bf[ni] = *reinterpret_cast<const bf16x8*>(Bt + ck + (wc * 64 + ni * 16 + l15) * 8);
#pragma unroll
    for (int mi = 0; mi < 4; ++mi)
#pragma unroll
      for (int ni = 0; ni < 4; ++ni)
        acc[mi][ni] = __builtin_amdgcn_mfma_f32_16x16x32_bf16(
            af[mi], bf[ni], acc[mi][ni], 0, 0, 0);
  }

  const float K1 = 2.8853900817779268f;  // (1/TEMP)*log2(e); shift -2 folded

  float Srow[4][4];
  float Scol[4] = {0.f, 0.f, 0.f, 0.f};
#pragma unroll
  for (int mi = 0; mi < 4; ++mi)
#pragma unroll
    for (int r = 0; r < 4; ++r) Srow[mi][r] = 0.f;

#pragma unroll
  for (int mi = 0; mi < 4; ++mi)
#pragma unroll
    for (int ni = 0; ni < 4; ++ni)
#pragma unroll
      for (int r = 0; r < 4; ++r) {
        const float v = __builtin_amdgcn_exp2f(fmaf(acc[mi][ni][r], K1, -K1));
        Srow[mi][r] += v;
        Scol[ni] += v;
      }

  // Diagonal tile: subtract self-similarity terms (exist only when wr==wc).
  if (diag) {
    if (wr == wc) {
#pragma unroll
      for (int mi = 0; mi < 4; ++mi)
#pragma unroll
        for (int r = 0; r < 4; ++r) {
          const float v = __builtin_amdgcn_exp2f(fmaf(acc[mi][mi][r], K1, -K1));
          if (l15 == q * 4 + r) Srow[mi][r] -= v;
        }
    }
  } else {
    // col sums (symmetric contribution): reduce over q, one atomic set.
#pragma unroll
    for (int ni = 0; ni < 4; ++ni) {
      float v = Scol[ni];
      v += __shfl_xor(v, 16, 64);
      v += __shfl_xor(v, 32, 64);
      if (q == 0)
        atomicAdd(&S[C0 + wc * 64 + ni * 16 + l15], v);
    }
  }

  // row sums: reduce over l15, one atomic per row
#pragma unroll
  for (int mi = 0; mi < 4; ++mi)
#pragma unroll
    for (int r = 0; r < 4; ++r) {
      float v = Srow[mi][r];
      v += __shfl_xor(v, 1, 64);
      v += __shfl_xor(v, 2, 64);
      v += __shfl_xor(v, 4, 64);
      v += __shfl_xor(v, 8, 64);
      if (l15 == 0)
        atomicAdd(&S[R0 + wr * 64 + mi * 16 + q * 4 + r], v);
    }

  // Positive-pair extraction (uniform branch; 32 of 2080 blocks).
  if (part) {
#pragma unroll
    for (int mi = 0; mi < 4; ++mi)
#pragma unroll
      for (int ni = 0; ni < 4; ++ni)
#pragma unroll
        for (int r = 0; r < 4; ++r) {
          const int rl = wr * 64 + mi * 16 + q * 4 + r;
          const int cl = wc * 64 + ni * 16 + l15;
          if (rl == cl) {
            const float p = 2.0f * acc[mi][ni][r];
            P[R0 + rl] = p;
            P[C0 + cl] = p;
          }
        }
  }
}

// ---------------------------------------------------------------------------
// Kernel 3: loss = mean_i( 2 + log(S_i) - P_i ). Single block, direct write.
// ---------------------------------------------------------------------------
__global__ __launch_bounds__(1024) void finalize_kernel(
    const float* __restrict__ S, const float* __restrict__ P,
    float* __restrict__ out)
{
  float c = 0.f;
  for (int i = threadIdx.x; i < NROWS; i += 1024)
    c += 2.0f + __logf(S[i]) - P[i];
#pragma unroll
  for (int off = 1; off < 64; off <<= 1)
    c += __shfl_xor(c, off, 64);
  __shared__ float wsum[16];
  const int lane = threadIdx.x & 63, w = threadIdx.x >> 6;
  if (lane == 0) wsum[w] = c;
  __syncthreads();
  if (threadIdx.x == 0) {
    float s = 0.f;
#pragma unroll
    for (int k = 0; k < 16; ++k) s += wsum[k];
    out[0] = s * (1.0f / NROWS);
  }
}

// ---------------------------------------------------------------------------
extern "C" void kernel_launch(void* const* d_in, const int* in_sizes, int n_in,
                              void* d_out, int out_size, void* d_ws, size_t ws_size,
                              hipStream_t stream)
{
  const float* zx = (const float*)d_in[0];
  const float* zy = (const float*)d_in[1];
  ushort* zn = (ushort*)d_ws;                                   // 2 MiB bf16 (k-major)
  float*  S  = (float*)((char*)d_ws + (size_t)NROWS * DIM * 2); // 32 KiB
  float*  P  = S + NROWS;                                       // 32 KiB
  float*  out = (float*)d_out;

  normalize_kernel<<<NROWS / 4, 256, 0, stream>>>(zx, zy, zn, S);
  simloss_kernel<<<2080, 256, 0, stream>>>(zn, S, P);
  finalize_kernel<<<1, 1024, 0, stream>>>(S, P, out);
}

// Round 6
// 95.505 us; speedup vs baseline: 1.0426x; 1.0426x over previous
//
#include <hip/hip_runtime.h>
#include <hip/hip_bf16.h>

#define BATCH 4096
#define NROWS 8192
#define DIM   128

typedef __bf16 bf16x8 __attribute__((ext_vector_type(8)));
typedef __bf16 bf16x2 __attribute__((ext_vector_type(2)));
typedef float  f32x4  __attribute__((ext_vector_type(4)));

typedef const __attribute__((address_space(1))) unsigned int* gptr_t;
typedef __attribute__((address_space(3))) unsigned int* lptr_t;

// HW fp32 atomic add (global_atomic_add_f32), no CAS loop, no return.
__device__ inline void atomAdd(float* p, float v) { unsafeAtomicAdd(p, v); }

// zn k-major per 128-row tile: (row r, col k) at
//   zn[(r>>7)*16384 + (k>>3)*1024 + (r&127)*8 + (k&7)]
// -> MFMA fragment (16 rows x 16B chunk) = 4x256B contiguous; B tile = 32 KB
//    contiguous, staged to LDS as a linear copy.

// ---------------------------------------------------------------------------
// Kernel 1: row-normalize -> bf16 zn (k-major), zero S. One wave per row.
// ---------------------------------------------------------------------------
__global__ __launch_bounds__(256) void normalize_kernel(
    const float* __restrict__ zx, const float* __restrict__ zy,
    ushort* __restrict__ zn, float* __restrict__ S)
{
  const int tid  = threadIdx.x;
  const int lane = tid & 63;
  const int w    = tid >> 6;
  const int row  = blockIdx.x * 4 + w;
  const float* src = (row < BATCH) ? (zx + (size_t)row * DIM)
                                   : (zy + (size_t)(row - BATCH) * DIM);
  float2 v = ((const float2*)src)[lane];
  float ss = v.x * v.x + v.y * v.y;
#pragma unroll
  for (int off = 1; off < 64; off <<= 1)
    ss += __shfl_xor(ss, off, 64);
  float inv = 1.0f / fmaxf(sqrtf(ss), 1e-8f);
  bf16x2 st;
  st.x = (__bf16)(v.x * inv);
  st.y = (__bf16)(v.y * inv);
  ushort* dst = zn + (size_t)(row >> 7) * 16384 + (row & 127) * 8;
  *reinterpret_cast<bf16x2*>(dst + (lane >> 2) * 1024 + (lane & 3) * 2) = st;
  if (lane == 0) S[row] = 0.f;
}

// ---------------------------------------------------------------------------
// Kernel 2: symmetric fused sim-GEMM + exp-sum. 520 blocks x exactly 4
// consecutive triangular tiles (perfect balance). A frags direct from
// k-major global (reloaded only on rb crossings); B tiles ping-pong through
// LDS, prefetch issued before compute (stage i+1 overlaps compute i).
// All S updates via HW fp32 atomics (no CAS loops).
// ---------------------------------------------------------------------------
__global__ __launch_bounds__(256, 2) void simloss_kernel(
    const ushort* __restrict__ zn, float* __restrict__ S, float* __restrict__ P)
{
  __shared__ ushort Ls[2][16384];   // 2 x 32 KiB linear B tiles

  const int tid  = threadIdx.x;
  const int lane = tid & 63;
  const int w    = tid >> 6;
  const int wr   = w >> 1, wc = w & 1;
  const int q    = lane >> 4;
  const int l15  = lane & 15;
  const float K1 = 2.8853900817779268f;  // (1/TEMP)*log2(e); shift -2 folded

  // decode first tile t0 -> (rb,cb); then increment through 4 tiles
  const int t0 = blockIdx.x * 4;
  int rb = (int)(0.5f * (129.0f - sqrtf((float)(16641 - 8 * t0))));
  while (rb * (129 - rb) / 2 > t0) --rb;
  while ((rb + 1) * (128 - rb) / 2 <= t0) ++rb;
  int cb = rb + (t0 - rb * (129 - rb) / 2);

  int rbs[4], cbs[4];
#pragma unroll
  for (int i = 0; i < 4; ++i) {
    rbs[i] = rb; cbs[i] = cb;
    if (++cb > 63) { ++rb; cb = rb; }
  }

  // linear 32 KB stage: lds dest = uniform base + lane*16
  auto stageB = [&](int tb, int buf) {
    const ushort* src = zn + (size_t)tb * 16384;
#pragma unroll
    for (int j = 0; j < 8; ++j) {
      const int off = (j * 256 + w * 64) * 8;          // wave-uniform (ushorts)
      __builtin_amdgcn_global_load_lds((gptr_t)(src + off + lane * 8),
                                       (lptr_t)(&Ls[buf][off]), 16, 0, 0);
    }
  };

  bf16x8 af[4][4];
  auto loadA = [&](int arb) {
#pragma unroll
    for (int ks = 0; ks < 4; ++ks) {
      const ushort* ap = zn + (size_t)arb * 16384 + (ks * 4 + q) * 1024
                       + (wr * 64 + l15) * 8;
#pragma unroll
      for (int mi = 0; mi < 4; ++mi)
        af[mi][ks] = *reinterpret_cast<const bf16x8*>(ap + mi * 16 * 8);
    }
  };

  float Srow[4][4];
#pragma unroll
  for (int mi = 0; mi < 4; ++mi)
#pragma unroll
    for (int r = 0; r < 4; ++r) Srow[mi][r] = 0.f;

  auto flushRows = [&](int arb) {
#pragma unroll
    for (int mi = 0; mi < 4; ++mi)
#pragma unroll
      for (int r = 0; r < 4; ++r) {
        float v = Srow[mi][r];
        v += __shfl_xor(v, 1, 64);
        v += __shfl_xor(v, 2, 64);
        v += __shfl_xor(v, 4, 64);
        v += __shfl_xor(v, 8, 64);
        if (l15 == 0)
          atomAdd(&S[arb * 128 + wr * 64 + mi * 16 + q * 4 + r], v);
        Srow[mi][r] = 0.f;
      }
  };

  stageB(cbs[0], 0);
  loadA(rbs[0]);
  int curA = rbs[0];
  __syncthreads();   // drains stage 0 (and A loads)

  for (int i = 0; i < 4; ++i) {
    if (i < 3) stageB(cbs[i + 1], (i + 1) & 1);   // overlaps compute below
    if (rbs[i] != curA) { flushRows(curA); loadA(rbs[i]); curA = rbs[i]; }

    const ushort* Bp = Ls[i & 1];
    const int C0 = cbs[i] * 128, R0 = rbs[i] * 128;
    const bool diag = (cbs[i] == rbs[i]);
    const bool part = (cbs[i] == rbs[i] + 32);

    f32x4 acc[4][4];
#pragma unroll
    for (int mi = 0; mi < 4; ++mi)
#pragma unroll
      for (int ni = 0; ni < 4; ++ni)
        acc[mi][ni] = (f32x4){0.f, 0.f, 0.f, 0.f};

#pragma unroll
    for (int ks = 0; ks < 4; ++ks) {
      const int ck = (ks * 4 + q) * 1024;
      bf16x8 bf[4];
#pragma unroll
      for (int ni = 0; ni < 4; ++ni)
        bf[ni] = *reinterpret_cast<const bf16x8*>(Bp + ck + (wc * 64 + ni * 16 + l15) * 8);
#pragma unroll
      for (int mi = 0; mi < 4; ++mi)
#pragma unroll
        for (int ni = 0; ni < 4; ++ni)
          acc[mi][ni] = __builtin_amdgcn_mfma_f32_16x16x32_bf16(
              af[mi][ks], bf[ni], acc[mi][ni], 0, 0, 0);
    }

    float Scol[4] = {0.f, 0.f, 0.f, 0.f};
#pragma unroll
    for (int mi = 0; mi < 4; ++mi)
#pragma unroll
      for (int ni = 0; ni < 4; ++ni)
#pragma unroll
        for (int r = 0; r < 4; ++r) {
          const float v = __builtin_amdgcn_exp2f(fmaf(acc[mi][ni][r], K1, -K1));
          Srow[mi][r] += v;
          Scol[ni] += v;
        }

    if (diag) {
      // subtract self-similarity terms (exist only when wr==wc); no col sums
      if (wr == wc) {
#pragma unroll
        for (int mi = 0; mi < 4; ++mi)
#pragma unroll
          for (int r = 0; r < 4; ++r) {
            const float v = __builtin_amdgcn_exp2f(fmaf(acc[mi][mi][r], K1, -K1));
            if (l15 == q * 4 + r) Srow[mi][r] -= v;
          }
      }
    } else {
#pragma unroll
      for (int ni = 0; ni < 4; ++ni) {
        float v = Scol[ni];
        v += __shfl_xor(v, 16, 64);
        v += __shfl_xor(v, 32, 64);
        if (q == 0)
          atomAdd(&S[C0 + wc * 64 + ni * 16 + l15], v);
      }
    }

    if (part) {
#pragma unroll
      for (int mi = 0; mi < 4; ++mi)
#pragma unroll
        for (int ni = 0; ni < 4; ++ni)
#pragma unroll
          for (int r = 0; r < 4; ++r) {
            const int rl = wr * 64 + mi * 16 + q * 4 + r;
            const int cl = wc * 64 + ni * 16 + l15;
            if (rl == cl) {
              const float p = 2.0f * acc[mi][ni][r];
              P[R0 + rl] = p;
              P[C0 + cl] = p;
            }
          }
    }

    __syncthreads();   // drains next prefetch; this buf's ds_reads complete
  }
  flushRows(curA);
}

// ---------------------------------------------------------------------------
// Kernel 3: loss = mean_i( 2 + log(S_i) - P_i ). Single block, direct write.
// ---------------------------------------------------------------------------
__global__ __launch_bounds__(1024) void finalize_kernel(
    const float* __restrict__ S, const float* __restrict__ P,
    float* __restrict__ out)
{
  float c = 0.f;
  for (int i = threadIdx.x; i < NROWS; i += 1024)
    c += 2.0f + __logf(S[i]) - P[i];
#pragma unroll
  for (int off = 1; off < 64; off <<= 1)
    c += __shfl_xor(c, off, 64);
  __shared__ float wsum[16];
  const int lane = threadIdx.x & 63, w = threadIdx.x >> 6;
  if (lane == 0) wsum[w] = c;
  __syncthreads();
  if (threadIdx.x == 0) {
    float s = 0.f;
#pragma unroll
    for (int k = 0; k < 16; ++k) s += wsum[k];
    out[0] = s * (1.0f / NROWS);
  }
}

// ---------------------------------------------------------------------------
extern "C" void kernel_launch(void* const* d_in, const int* in_sizes, int n_in,
                              void* d_out, int out_size, void* d_ws, size_t ws_size,
                              hipStream_t stream)
{
  const float* zx = (const float*)d_in[0];
  const float* zy = (const float*)d_in[1];
  ushort* zn = (ushort*)d_ws;                                   // 2 MiB bf16 (k-major)
  float*  S  = (float*)((char*)d_ws + (size_t)NROWS * DIM * 2); // 32 KiB
  float*  P  = S + NROWS;                                       // 32 KiB
  float*  out = (float*)d_out;

  normalize_kernel<<<NROWS / 4, 256, 0, stream>>>(zx, zy, zn, S);
  simloss_kernel<<<520, 256, 0, stream>>>(zn, S, P);
  finalize_kernel<<<1, 1024, 0, stream>>>(S, P, out);
}